// Round 4
// baseline (388.735 us; speedup 1.0000x reference)
//
#include <hip/hip_runtime.h>
#include <hip/hip_bf16.h>

typedef __attribute__((ext_vector_type(8))) short short8;
typedef __attribute__((ext_vector_type(4))) float floatx4;
typedef unsigned short u16;

#define NB 32
#define NN 1536
#define NM 80
#define NH 8
#define NC 64
#define NINNER 512
#define NQD 320
#define NKD 768

__device__ __forceinline__ float bf2f(u16 u) {
    union { unsigned i; float f; } x; x.i = ((unsigned)u) << 16; return x.f;
}
__device__ __forceinline__ u16 f2bf(float f) {
    unsigned u = __float_as_uint(f);
    unsigned r = (u + 0x7FFFu + ((u >> 16) & 1u)) >> 16;  // RNE
    return (u16)r;
}
__device__ __forceinline__ short8 cvt8(const float* __restrict__ p) {
    float4 a = ((const float4*)p)[0];
    float4 b = ((const float4*)p)[1];
    short8 r;
    r[0] = (short)f2bf(a.x); r[1] = (short)f2bf(a.y);
    r[2] = (short)f2bf(a.z); r[3] = (short)f2bf(a.w);
    r[4] = (short)f2bf(b.x); r[5] = (short)f2bf(b.y);
    r[6] = (short)f2bf(b.z); r[7] = (short)f2bf(b.w);
    return r;
}
__device__ __forceinline__ void gload16(const u16* g, u16* l) {
    __builtin_amdgcn_global_load_lds(
        (const __attribute__((address_space(1))) unsigned int*)g,
        (__attribute__((address_space(3))) unsigned int*)l, 16, 0, 0);
}

// ---------------------------------------------------------------------------
// Input dtype detect: flag=1 means float tensors are f32.
// ---------------------------------------------------------------------------
__global__ __launch_bounds__(256) void detect_dtype(const u16* __restrict__ x,
                                                    int* __restrict__ flag) {
    __shared__ int cnt;
    if (threadIdx.x == 0) cnt = 0;
    __syncthreads();
    int c = 0;
    for (int i = threadIdx.x; i < 8192; i += 256) {
        unsigned e = (x[i] >> 7) & 0xFF;
        if (e >= 0xA0) c++;
    }
    atomicAdd(&cnt, c);
    __syncthreads();
    if (threadIdx.x == 0) *flag = (cnt > 64) ? 1 : 0;
}

// ---------------------------------------------------------------------------
// Mask prep (self-detecting storage dtype) -> f32 additive bias per (b,m).
// ---------------------------------------------------------------------------
__global__ __launch_bounds__(256) void mask_prep(const unsigned char* __restrict__ raw,
                                                 float* __restrict__ maskbias) {
    __shared__ int c_bf, c_f32, c_u8;
    if (threadIdx.x == 0) { c_bf = 0; c_f32 = 0; c_u8 = 0; }
    __syncthreads();
    for (int i = threadIdx.x; i < NB * NM; i += 256) {
        unsigned char v = raw[i];
        if (v == 0x3F && (i & 3) == 1) atomicAdd(&c_bf, 1);
        if (v == 0x3F && (i & 3) == 3) atomicAdd(&c_f32, 1);
        if (v != 0 && (i & 3) != 0) atomicAdd(&c_u8, 1);
    }
    __syncthreads();
    int md;
    if (c_bf > 0) md = 2;
    else if (c_f32 > 0) md = 3;
    else if (c_u8 > 0) md = 1;
    else md = 0;
    for (int i = threadIdx.x; i < NB * NM; i += 256) {
        bool on;
        if (md == 2) on = ((const u16*)raw)[i] != 0;
        else if (md == 3) on = ((const float*)raw)[i] != 0.0f;
        else if (md == 1) on = raw[i] != 0;
        else on = ((const int*)raw)[i] != 0;
        maskbias[i] = on ? 0.0f : -3.4028234663852886e38f;
    }
}

// ---------------------------------------------------------------------------
// Batched f32->bf16 conversion for the weight matrices only.
// ---------------------------------------------------------------------------
struct ConvSeg { const void* src; u16* dst; int nblk; };
struct ConvArgs { ConvSeg s[4]; };

__global__ __launch_bounds__(256) void conv_batch(ConvArgs a, const int* __restrict__ flag) {
    const int f = *flag;
    int b = blockIdx.x, seg = 0;
    while (seg < 4 && b >= a.s[seg].nblk) { b -= a.s[seg].nblk; seg++; }
    if (seg >= 4) return;
    const long idx = (long)b * 2048 + threadIdx.x * 8;
    u16* dst = a.s[seg].dst;
    if (f) *(short8*)(dst + idx) = cvt8((const float*)a.s[seg].src + idx);
    else   *(short8*)(dst + idx) = *(const short8*)((const u16*)a.s[seg].src + idx);
}

// ---------------------------------------------------------------------------
// m97-style bf16 MFMA GEMM: C[M x N] = A[M x K] @ B[N x K]^T, bf16 out.
// A is f32 (flag=1) or bf16, converted during VGPR->LDS staging; B is bf16
// staged via global_load_lds width=16 with XOR chunk swizzle. 128x128 tile,
// BK=32, 4 waves 2x2 each 64x64. Grid (M/128, N/128 [, 2 if DUAL]).
// ---------------------------------------------------------------------------
template <bool DUAL>
__global__ __launch_bounds__(256) void gemm128(const void* __restrict__ A,
                                               const u16* __restrict__ B,
                                               u16* __restrict__ C,
                                               const void* __restrict__ A2,
                                               const u16* __restrict__ B2,
                                               u16* __restrict__ C2,
                                               int Ncols, int K,
                                               const int* __restrict__ flag) {
    __shared__ __align__(16) u16 As[128 * 32];
    __shared__ __align__(16) u16 Bs[128 * 32];
    if (DUAL && blockIdx.z) { A = A2; B = B2; C = C2; }
    const int f = *flag;
    const int tid = threadIdx.x;
    const int wave = tid >> 6, lane = tid & 63;
    const int l16 = lane & 15, quad = lane >> 4;
    const int wr = wave >> 1, wc = wave & 1;
    const int bm0 = blockIdx.x * 128, bn0 = blockIdx.y * 128;

    const int r0 = tid >> 2, c0 = tid & 3;
    const int sc = c0 ^ ((r0 >> 1) & 3);            // swizzled source chunk
    const u16* Bg = B + (size_t)(bn0 + r0) * K + sc * 8;
    u16* BsW = Bs + wave * 512;
    u16* AsD = As + wave * 512 + (size_t)(lane) * 8; // this thread's LDS slot
    const size_t aoff = (size_t)(bm0 + r0) * K + sc * 8;

    const int swz = (l16 >> 1) & 3;
    floatx4 acc[4][4];
#pragma unroll
    for (int i = 0; i < 4; ++i)
#pragma unroll
        for (int n = 0; n < 4; ++n) acc[i][n] = (floatx4)0.0f;

    for (int kk = 0; kk < K; kk += 32) {
        __syncthreads();                            // WAR: prev reads done
#pragma unroll
        for (int j = 0; j < 2; ++j) {
            short8 av;
            if (f) av = cvt8((const float*)A + aoff + (size_t)(j * 64) * K + kk);
            else   av = *(const short8*)((const u16*)A + aoff + (size_t)(j * 64) * K + kk);
            *(short8*)(AsD + j * 2048) = av;
            gload16(Bg + (size_t)(j * 64) * K + kk, BsW + j * 2048);
        }
        __syncthreads();                            // drains vm+lgkm
        short8 af[4], bf[4];
#pragma unroll
        for (int i = 0; i < 4; ++i)
            af[i] = *(const short8*)&As[(wr * 64 + i * 16 + l16) * 32 + ((quad ^ swz) * 8)];
#pragma unroll
        for (int n = 0; n < 4; ++n)
            bf[n] = *(const short8*)&Bs[(wc * 64 + n * 16 + l16) * 32 + ((quad ^ swz) * 8)];
#pragma unroll
        for (int i = 0; i < 4; ++i)
#pragma unroll
            for (int n = 0; n < 4; ++n)
                acc[i][n] = __builtin_amdgcn_mfma_f32_16x16x32_bf16(af[i], bf[n], acc[i][n], 0, 0, 0);
    }

#pragma unroll
    for (int n = 0; n < 4; ++n) {
        const int col = bn0 + wc * 64 + n * 16 + l16;
#pragma unroll
        for (int i = 0; i < 4; ++i)
#pragma unroll
            for (int r = 0; r < 4; ++r) {
                const int row = bm0 + wr * 64 + i * 16 + quad * 4 + r;
                C[(size_t)row * Ncols + col] = f2bf(acc[i][n][r]);
            }
    }
}

// ---------------------------------------------------------------------------
// V transpose into (b,h,c,m) with K padded 80->96 (zeros). Internal bf16.
// ---------------------------------------------------------------------------
__global__ __launch_bounds__(256) void transpose_v(const u16* __restrict__ v,
                                                   u16* __restrict__ vT) {
    int b = blockIdx.x >> 3, h = blockIdx.x & 7;
    const u16* src = v + (size_t)b * NM * NINNER + h * NC;
    u16* o = vT + (size_t)(b * NH + h) * NC * 96;
    for (int idx = threadIdx.x; idx < NM * NC; idx += 256) {
        int m = idx >> 6, c = idx & 63;
        o[c * 96 + m] = src[(size_t)m * NINNER + c];
    }
    for (int idx = threadIdx.x; idx < NC * 16; idx += 256) {
        int c = idx >> 4, m = 80 + (idx & 15);
        o[c * 96 + m] = 0;
    }
}

// ---------------------------------------------------------------------------
// Fused attention + O-projection. Block = (64 rows n, batch b), all 8 heads.
// Per head: QK^T (MFMA) -> bias+softmax -> P@V (MFMA) -> per-head 64x64 slab
// to LDS -> accumulate out[64x320] += slab @ Wo[:, h*64:h*64+64]^T in regs.
// Epilogue: + bo, store f32/bf16 per flag. Kills the ao intermediate.
// ---------------------------------------------------------------------------
__global__ __launch_bounds__(256) void attn_fused(const u16* __restrict__ q,
                                                  const u16* __restrict__ k,
                                                  const u16* __restrict__ vT,
                                                  const float* __restrict__ maskbias,
                                                  const void* __restrict__ box,
                                                  const void* __restrict__ road,
                                                  const u16* __restrict__ Wo,
                                                  const void* __restrict__ bo,
                                                  void* __restrict__ out,
                                                  const int* __restrict__ flag) {
    const int f = *flag;
    const int n0 = blockIdx.x * 64;
    const int b = blockIdx.y;
    const int tid = threadIdx.x;
    const int wave = tid >> 6, lane = tid & 63;
    const int l16 = lane & 15, quad = lane >> 4;

    __shared__ __align__(16) u16 p_lds[64][104];  // P, K padded 80->96
    __shared__ __align__(16) u16 oh_s[64][72];    // per-head attn output slab

    // zero P pad cols 80..95 once (each wave its own rows; no barrier needed)
    {
        int row = 16 * wave + (lane >> 2);
        int col = 80 + (lane & 3) * 4;
        ushort4 z; z.x = 0; z.y = 0; z.z = 0; z.w = 0;
        *(ushort4*)&p_lds[row][col] = z;
    }

    // hoisted per-row/per-col bias: add[mt][r] = maskbias + 5*box + 5*road
    float add[5][4];
#pragma unroll
    for (int r = 0; r < 4; ++r) {
        const int n = n0 + 16 * wave + quad * 4 + r;
        const size_t ridx = (size_t)b * NN + n;
        const float roadv = 5.0f * (f ? ((const float*)road)[ridx]
                                      : bf2f(((const u16*)road)[ridx]));
#pragma unroll
        for (int mt = 0; mt < 5; ++mt) {
            const int m = mt * 16 + l16;
            const size_t bidx = ridx * NM + m;
            const float boxv = 5.0f * (f ? ((const float*)box)[bidx]
                                         : bf2f(((const u16*)box)[bidx]));
            add[mt][r] = maskbias[b * NM + m] + boxv + roadv;
        }
    }
    float bov[5];
#pragma unroll
    for (int j = 0; j < 5; ++j) {
        const int col = (wave * 5 + j) * 16 + l16;
        bov[j] = f ? ((const float*)bo)[col] : bf2f(((const u16*)bo)[col]);
    }

    floatx4 accO[4][5];
#pragma unroll
    for (int i = 0; i < 4; ++i)
#pragma unroll
        for (int j = 0; j < 5; ++j) accO[i][j] = (floatx4)0.0f;

    for (int h = 0; h < NH; ++h) {
        // ---- QK^T: wave's 16 rows x 80 boxes
        floatx4 s[5];
#pragma unroll
        for (int i = 0; i < 5; ++i) s[i] = (floatx4)0.0f;
        const size_t qrow = (size_t)(b * NN + n0 + 16 * wave + l16) * NINNER + h * NC;
#pragma unroll
        for (int kk = 0; kk < NC; kk += 32) {
            short8 a = *(const short8*)(q + qrow + kk + quad * 8);
#pragma unroll
            for (int mt = 0; mt < 5; ++mt) {
                short8 bf = *(const short8*)(k + (size_t)(b * NM + mt * 16 + l16) * NINNER + h * NC + kk + quad * 8);
                s[mt] = __builtin_amdgcn_mfma_f32_16x16x32_bf16(a, bf, s[mt], 0, 0, 0);
            }
        }

        // ---- bias + softmax over M=80 (reduce across 16 lanes)
        float sv[5][4], inv[4];
#pragma unroll
        for (int r = 0; r < 4; ++r) {
#pragma unroll
            for (int mt = 0; mt < 5; ++mt)
                sv[mt][r] = s[mt][r] * 0.125f + add[mt][r];
            float mx = sv[0][r];
#pragma unroll
            for (int mt = 1; mt < 5; ++mt) mx = fmaxf(mx, sv[mt][r]);
#pragma unroll
            for (int off = 1; off < 16; off <<= 1) mx = fmaxf(mx, __shfl_xor(mx, off, 16));
            float sum = 0.0f;
#pragma unroll
            for (int mt = 0; mt < 5; ++mt) {
                float p = __expf(sv[mt][r] - mx);
                sv[mt][r] = p;
                sum += p;
            }
#pragma unroll
            for (int off = 1; off < 16; off <<= 1) sum += __shfl_xor(sum, off, 16);
            inv[r] = 1.0f / sum;
        }

        // ---- P -> LDS (own rows only: no barrier, wave-local dependency)
#pragma unroll
        for (int r = 0; r < 4; ++r) {
            const int lr = 16 * wave + quad * 4 + r;
#pragma unroll
            for (int mt = 0; mt < 5; ++mt) p_lds[lr][mt * 16 + l16] = f2bf(sv[mt][r]);
        }

        // ---- P @ V (own 16 rows x 64 head-dims)
        floatx4 o[4];
#pragma unroll
        for (int i = 0; i < 4; ++i) o[i] = (floatx4)0.0f;
        const u16* vbase = vT + (size_t)(b * NH + h) * NC * 96;
#pragma unroll
        for (int kk = 0; kk < 96; kk += 32) {
            short8 a = *(const short8*)&p_lds[16 * wave + l16][kk + quad * 8];
#pragma unroll
            for (int nt = 0; nt < 4; ++nt) {
                short8 bf = *(const short8*)(vbase + (size_t)(nt * 16 + l16) * 96 + kk + quad * 8);
                o[nt] = __builtin_amdgcn_mfma_f32_16x16x32_bf16(a, bf, o[nt], 0, 0, 0);
            }
        }

        // ---- normalized per-head slab -> LDS
#pragma unroll
        for (int nt = 0; nt < 4; ++nt)
#pragma unroll
            for (int r = 0; r < 4; ++r)
                oh_s[16 * wave + quad * 4 + r][nt * 16 + l16] = f2bf(o[nt][r] * inv[r]);
        __syncthreads();  // slab complete, visible to all waves

        // ---- out += slab @ Wo[:, h*64 : h*64+64]^T  (wave owns 80 cols)
#pragma unroll
        for (int kk2 = 0; kk2 < 64; kk2 += 32) {
            short8 a2[4];
#pragma unroll
            for (int i = 0; i < 4; ++i)
                a2[i] = *(const short8*)&oh_s[i * 16 + l16][kk2 + quad * 8];
#pragma unroll
            for (int j = 0; j < 5; ++j) {
                short8 b2 = *(const short8*)(Wo + (size_t)((wave * 5 + j) * 16 + l16) * NINNER + h * NC + kk2 + quad * 8);
#pragma unroll
                for (int i = 0; i < 4; ++i)
                    accO[i][j] = __builtin_amdgcn_mfma_f32_16x16x32_bf16(a2[i], b2, accO[i][j], 0, 0, 0);
            }
        }
        __syncthreads();  // all reads done before next head overwrites slab
    }

    // ---- epilogue: + bo, store
#pragma unroll
    for (int i = 0; i < 4; ++i)
#pragma unroll
        for (int j = 0; j < 5; ++j) {
            const int col = (wave * 5 + j) * 16 + l16;
#pragma unroll
            for (int r = 0; r < 4; ++r) {
                const int row = n0 + i * 16 + quad * 4 + r;
                const float val = accO[i][j][r] + bov[j];
                const size_t oidx = (size_t)(b * NN + row) * NQD + col;
                if (f) ((float*)out)[oidx] = val;
                else   ((u16*)out)[oidx] = f2bf(val);
            }
        }
}

extern "C" void kernel_launch(void* const* d_in, const int* in_sizes, int n_in,
                              void* d_out, int out_size, void* d_ws, size_t ws_size,
                              hipStream_t stream) {
    (void)in_sizes; (void)n_in; (void)out_size; (void)ws_size;
    const void* x    = d_in[0];
    const void* key  = d_in[1];
    const void* val  = d_in[2];
    const unsigned char* mask = (const unsigned char*)d_in[3];
    const void* box  = d_in[4];
    const void* road = d_in[5];
    const void* Wq   = d_in[6];
    const void* Wk   = d_in[7];
    const void* Wv   = d_in[8];
    const void* Wo   = d_in[9];
    const void* bo   = d_in[10];

    char* ws = (char*)d_ws;
    size_t off = 0;
    auto carve = [&](size_t bytes) {
        char* p = ws + off;
        off += (bytes + 255) & ~(size_t)255;
        return p;
    };
    int* flag   = (int*)carve(256);
    u16* q_ws   = (u16*)carve((size_t)NB * NN * NINNER * 2);   // 50.3 MB
    u16* k_ws   = (u16*)carve((size_t)NB * NM * NINNER * 2);   // 2.6 MB
    u16* v_ws   = (u16*)carve((size_t)NB * NM * NINNER * 2);   // 2.6 MB
    u16* vT_ws  = (u16*)carve((size_t)NB * NH * NC * 96 * 2);  // 3.1 MB
    u16* Wq_bf  = (u16*)carve((size_t)NINNER * NQD * 2);
    u16* Wk_bf  = (u16*)carve((size_t)NINNER * NKD * 2);
    u16* Wv_bf  = (u16*)carve((size_t)NINNER * NKD * 2);
    u16* Wo_bf  = (u16*)carve((size_t)NQD * NINNER * 2);
    float* mb   = (float*)carve((size_t)NB * NM * 4);

    detect_dtype<<<1, 256, 0, stream>>>((const u16*)x, flag);
    mask_prep<<<1, 256, 0, stream>>>(mask, mb);

    ConvArgs ca;
    ca.s[0] = { Wq, Wq_bf, (int)((size_t)NINNER * NQD / 2048) };  // 80
    ca.s[1] = { Wk, Wk_bf, (int)((size_t)NINNER * NKD / 2048) };  // 192
    ca.s[2] = { Wv, Wv_bf, (int)((size_t)NINNER * NKD / 2048) };  // 192
    ca.s[3] = { Wo, Wo_bf, (int)((size_t)NQD * NINNER / 2048) };  // 80
    conv_batch<<<544, 256, 0, stream>>>(ca, flag);

    // q = x @ Wq^T : (49152 x 320) @ (512 x 320)^T, A converted in-staging
    gemm128<false><<<dim3(NB * NN / 128, NINNER / 128), 256, 0, stream>>>(
        x, Wq_bf, q_ws, nullptr, nullptr, nullptr, NINNER, NQD, flag);
    // k/v = {key,value} @ {Wk,Wv}^T : (2560 x 768) @ (512 x 768)^T, dual
    gemm128<true><<<dim3(NB * NM / 128, NINNER / 128, 2), 256, 0, stream>>>(
        key, Wk_bf, k_ws, val, Wv_bf, v_ws, NINNER, NKD, flag);
    transpose_v<<<NB * NH, 256, 0, stream>>>(v_ws, vT_ws);
    // attention + O-projection fused, writes final output (+bo)
    attn_fused<<<dim3(NN / 64, NB), 256, 0, stream>>>(
        q_ws, k_ws, vT_ws, mb, box, road, Wo_bf, bo, d_out, flag);
}